// Round 6
// baseline (47.918 us; speedup 1.0000x reference)
//
#include <hip/hip_runtime.h>
#include <stdint.h>

typedef __attribute__((ext_vector_type(8))) short short8;
typedef __attribute__((ext_vector_type(4))) float f32x4;

#define SEQ 256
#define NH 8

__device__ __forceinline__ uint32_t cvt_pk_bf16(float lo, float hi) {
  uint32_t r;
  asm("v_cvt_pk_bf16_f32 %0, %1, %2" : "=v"(r) : "v"(lo), "v"(hi));
  return r;
}

__device__ __forceinline__ short8 pack8(f32x4 a, f32x4 b) {
  union { uint32_t u[4]; short8 v; } t;
  t.u[0] = cvt_pk_bf16(a[0], a[1]);
  t.u[1] = cvt_pk_bf16(a[2], a[3]);
  t.u[2] = cvt_pk_bf16(b[0], b[1]);
  t.u[3] = cvt_pk_bf16(b[2], b[3]);
  return t.v;
}

// ---------------------------------------------------------------------------
// Fused kernel, high-occupancy variant. Block = (b, h, 32m x 32n), 256 thr
// (4 waves), 2048 blocks. LDS 18.4 KB -> up to 8 blocks/CU; launch_bounds
// (256,6) targets VGPR<=85 for ~6 waves/SIMD.
// Phase 1 (per block, via MFMA, conventions validated r5):
//   sAp[rl][k]: rl = m_loc-n_loc+31 (63 rows + junk row 63), f = f0+rl
//   sAi[m_loc][k], sAj[n_loc][k]
// Phase 2: per 4-mi group: e1=relu(Ap+Ai+Aj)->bf16, mfma(A=w2^T)->e2^T,
//   relu-dot w3; NEW butterfly-exchange reduce (2x shfl16 + 1x shfl32 +
//   4 cndmask) -> lane(kb,lcol) holds cell (mb+kb, n0+ng*16+lcol).
// ---------------------------------------------------------------------------
__global__ __launch_bounds__(256, 6) void dis_att_fused(
    const float* __restrict__ attn, const int* __restrict__ bseq,
    const int* __restrict__ cseq, const float* __restrict__ epos,
    const float* __restrict__ ebi, const float* __restrict__ ebj,
    const float* __restrict__ eci, const float* __restrict__ ecj,
    const float* __restrict__ w1, const float* __restrict__ w2,
    const float* __restrict__ w3, float* __restrict__ out) {
  __shared__ float sAp[64][36];
  __shared__ float sAi[32][36];
  __shared__ float sAj[32][36];
  int tid = threadIdx.x;
  int wg = blockIdx.x;                     // 2048 = b(4) h(8) mt(8) nt(8)
  int nt = wg & 7, mt = (wg >> 3) & 7, h = (wg >> 6) & 7, b = wg >> 9;
  int m0 = mt * 32, n0 = nt * 32;
  int f0 = m0 - n0 + 225;                  // global f of sAp row 0
  int lane = tid & 63, w = tid >> 6;       // 4 waves
  int lcol = lane & 15, kb = lane >> 4, k8 = kb * 8;
  f32x4 zero = {0.f, 0.f, 0.f, 0.f};

  // ---------------- phase 1: build tables (4 waves) ----------------
  {
    // Ap: wave w builds tile w (rows w*16 .. w*16+15)
    short8 bpos[2];
#pragma unroll
    for (int kt = 0; kt < 2; ++kt) {
      union { uint32_t u[4]; short8 v; } t;
#pragma unroll
      for (int r = 0; r < 4; ++r) {
        float lo = w1[(k8 + 2 * r) * 256 + (kt * 16 + lcol) * 8 + h];
        float hi = w1[(k8 + 2 * r + 1) * 256 + (kt * 16 + lcol) * 8 + h];
        t.u[r] = cvt_pk_bf16(lo, hi);
      }
      bpos[kt] = t.v;
    }
    int frow = f0 + w * 16 + lcol;
    if (frow > 511) frow = 511;            // only junk row 63 hits this
    const float* ep = epos + (frow * NH + h) * 32 + k8;
    short8 af = pack8(*(const f32x4*)ep, *(const f32x4*)(ep + 4));
#pragma unroll
    for (int kt = 0; kt < 2; ++kt) {
      f32x4 d = __builtin_amdgcn_mfma_f32_16x16x32_bf16(af, bpos[kt], zero, 0, 0, 0);
#pragma unroll
      for (int r = 0; r < 4; ++r)
        sAp[w * 16 + kb * 4 + r][kt * 16 + lcol] = d[r];
    }

    // Ai (waves 0,1) / Aj (waves 2,3), tile t = w&1 (rows t*16 .. t*16+15)
    int isI = w < 2;
    int t_ = w & 1;
    int p0 = isI ? ((kb < 2 ? 32 : 48) + k8)    // W_i rows 32..47 | 64..79
                 : ((kb < 2 ? 48 : 64) + k8);   // W_j rows 48..63 | 80..95
    short8 bw[2];
#pragma unroll
    for (int kt = 0; kt < 2; ++kt) {
      union { uint32_t u[4]; short8 v; } t;
#pragma unroll
      for (int r = 0; r < 4; ++r) {
        float lo = w1[(p0 + 2 * r) * 256 + (kt * 16 + lcol) * 8 + h];
        float hi = w1[(p0 + 2 * r + 1) * 256 + (kt * 16 + lcol) * 8 + h];
        t.u[r] = cvt_pk_bf16(lo, hi);
      }
      bw[kt] = t.v;
    }
    const float* eB = isI ? ebi : ebj;
    const float* eC = isI ? eci : ecj;
    int base = isI ? m0 : n0;
    int gm = b * SEQ + base + t_ * 16 + lcol;
    int bi = bseq[gm], ci = cseq[gm];
    const float* src = (kb < 2) ? eB + (bi * NH + h) * 16 + k8
                                : eC + (ci * NH + h) * 16 + (k8 - 16);
    short8 ae = pack8(*(const f32x4*)src, *(const f32x4*)(src + 4));
#pragma unroll
    for (int kt = 0; kt < 2; ++kt) {
      f32x4 d = __builtin_amdgcn_mfma_f32_16x16x32_bf16(ae, bw[kt], zero, 0, 0, 0);
#pragma unroll
      for (int r = 0; r < 4; ++r) {
        if (isI) sAi[t_ * 16 + kb * 4 + r][kt * 16 + lcol] = d[r];
        else     sAj[t_ * 16 + kb * 4 + r][kt * 16 + lcol] = d[r];
      }
    }
  }
  __syncthreads();

  // ---------------- phase 2: main compute ----------------
  union { uint32_t u[4]; short8 v; } w2f;  // A = w2^T: row=lcol(l), k=k8..k8+7
#pragma unroll
  for (int r = 0; r < 4; ++r) {
    float lo = w2[(k8 + 2 * r) * 128 + lcol * 8 + h];
    float hi = w2[(k8 + 2 * r + 1) * 128 + lcol * 8 + h];
    w2f.u[r] = cvt_pk_bf16(lo, hi);
  }
  float w3v[4];
#pragma unroll
  for (int r = 0; r < 4; ++r) w3v[r] = w3[(kb * 4 + r) * 8 + h];

  const float* attn_b = attn + (b * NH + h) * SEQ * SEQ;
  float* out_b = out + (b * NH + h) * SEQ * SEQ;
  int bit4 = kb & 1, bit5 = kb & 2;

#pragma unroll
  for (int g = 0; g < 4; ++g) {            // mi4 = g>>1, ng = g&1
    int mb = w * 8 + (g >> 1) * 4;
    int ncol = (g & 1) * 16 + lcol;
    int idx = (m0 + mb + kb) * SEQ + n0 + ncol;
    float av = attn_b[idx];
    f32x4 aj0 = *(const f32x4*)&sAj[ncol][k8];
    f32x4 aj1 = *(const f32x4*)&sAj[ncol][k8 + 4];
    float part[4];
#pragma unroll
    for (int mi = 0; mi < 4; ++mi) {
      int rl = mb + mi - ncol + 31;
      f32x4 p0 = *(const f32x4*)&sAp[rl][k8];
      f32x4 p1 = *(const f32x4*)&sAp[rl][k8 + 4];
      f32x4 i0 = *(const f32x4*)&sAi[mb + mi][k8];
      f32x4 i1 = *(const f32x4*)&sAi[mb + mi][k8 + 4];
      f32x4 s0 = p0 + i0 + aj0;
      f32x4 s1 = p1 + i1 + aj1;
      union { uint32_t u[4]; short8 v; } ef;
      ef.u[0] = cvt_pk_bf16(fmaxf(s0[0], 0.f), fmaxf(s0[1], 0.f));
      ef.u[1] = cvt_pk_bf16(fmaxf(s0[2], 0.f), fmaxf(s0[3], 0.f));
      ef.u[2] = cvt_pk_bf16(fmaxf(s1[0], 0.f), fmaxf(s1[1], 0.f));
      ef.u[3] = cvt_pk_bf16(fmaxf(s1[2], 0.f), fmaxf(s1[3], 0.f));
      f32x4 d = __builtin_amdgcn_mfma_f32_16x16x32_bf16(w2f.v, ef.v, zero, 0, 0, 0);
      part[mi] = fmaxf(d[0], 0.f) * w3v[0] + fmaxf(d[1], 0.f) * w3v[1] +
                 fmaxf(d[2], 0.f) * w3v[2] + fmaxf(d[3], 0.f) * w3v[3];
    }
    // butterfly-exchange reduce: lane(kb) <- sum over quarters of part[kb]
    float mineA = bit4 ? part[1] : part[0];
    float sendA = bit4 ? part[0] : part[1];
    float mineB = bit4 ? part[3] : part[2];
    float sendB = bit4 ? part[2] : part[3];
    mineA += __shfl_xor(sendA, 16, 64);
    mineB += __shfl_xor(sendB, 16, 64);
    float keep = bit5 ? mineB : mineA;
    float send = bit5 ? mineA : mineB;
    float res = keep + __shfl_xor(send, 32, 64);
    out_b[idx] = av + res;
  }
}

extern "C" void kernel_launch(void* const* d_in, const int* in_sizes, int n_in,
                              void* d_out, int out_size, void* d_ws, size_t ws_size,
                              hipStream_t stream) {
  const float* attn = (const float*)d_in[0];
  const int* bseq   = (const int*)d_in[1];
  const int* cseq   = (const int*)d_in[2];
  const float* epos = (const float*)d_in[3];
  const float* ebi  = (const float*)d_in[4];
  const float* ebj  = (const float*)d_in[5];
  const float* eci  = (const float*)d_in[6];
  const float* ecj  = (const float*)d_in[7];
  const float* w1   = (const float*)d_in[8];
  const float* w2   = (const float*)d_in[9];
  const float* w3   = (const float*)d_in[10];
  float* out = (float*)d_out;

  hipLaunchKernelGGL(dis_att_fused, dim3(2048), dim3(256), 0, stream,
                     attn, bseq, cseq, epos, ebi, ebj, eci, ecj, w1, w2, w3, out);
}

// Round 7
// 26.548 us; speedup vs baseline: 1.8050x; 1.8050x over previous
//
#include <hip/hip_runtime.h>
#include <stdint.h>

typedef __attribute__((ext_vector_type(8))) short short8;
typedef __attribute__((ext_vector_type(4))) float f32x4;

#define SEQ 256
#define NH 8

__device__ __forceinline__ uint32_t cvt_pk_bf16(float lo, float hi) {
  uint32_t r;
  asm("v_cvt_pk_bf16_f32 %0, %1, %2" : "=v"(r) : "v"(lo), "v"(hi));
  return r;
}

__device__ __forceinline__ short8 pack8(f32x4 a, f32x4 b) {
  union { uint32_t u[4]; short8 v; } t;
  t.u[0] = cvt_pk_bf16(a[0], a[1]);
  t.u[1] = cvt_pk_bf16(a[2], a[3]);
  t.u[2] = cvt_pk_bf16(b[0], b[1]);
  t.u[3] = cvt_pk_bf16(b[2], b[3]);
  return t.v;
}

// ---------------------------------------------------------------------------
// ONE fused kernel (r5 geometry, ILP-forced phase 2).
// Block = (b, h, 64m x 64n), 512 thr (8 waves), 512 blocks.
// Phase 1 (identical to validated r5): build pre-ReLU layer-1 tables via MFMA
//   into LDS: sAp[rl][k] (rl=m-n+63, 128 rows, row127 junk), sAi, sAj.
// Phase 2: per ng-group batch-load ALL operands (pA/pB[4]) into registers,
//   sched_barrier, then 4 independent e1->mfma->dot chains, 3-shfl butterfly
//   reduce (validated r6), coalesced attn-add store.
// ---------------------------------------------------------------------------
__global__ __launch_bounds__(512, 4) void dis_att_fused(
    const float* __restrict__ attn, const int* __restrict__ bseq,
    const int* __restrict__ cseq, const float* __restrict__ epos,
    const float* __restrict__ ebi, const float* __restrict__ ebj,
    const float* __restrict__ eci, const float* __restrict__ ecj,
    const float* __restrict__ w1, const float* __restrict__ w2,
    const float* __restrict__ w3, float* __restrict__ out) {
  __shared__ float sAp[128][36];
  __shared__ float sAi[64][36];
  __shared__ float sAj[64][36];
  int tid = threadIdx.x;
  int wg = blockIdx.x;                     // 512 = b(4) h(8) mt(4) nt(4)
  int nt = wg & 3, mt = (wg >> 2) & 3, h = (wg >> 4) & 7, b = wg >> 7;
  int m0 = mt * 64, n0 = nt * 64;
  int f0 = m0 - n0 + 193;                  // global f of sAp row 0
  int lane = tid & 63, w = tid >> 6;
  int lcol = lane & 15, kb = lane >> 4, k8 = kb * 8;
  f32x4 zero = {0.f, 0.f, 0.f, 0.f};

  // ---------------- phase 1: build tables (validated r5) ----------------
  if (w < 4) {                             // Apos band: m-tiles {w, w+4} x kk{0,1}
    short8 bf[2];
#pragma unroll
    for (int kt = 0; kt < 2; ++kt) {       // B = W_pos[k=p][kk]
      union { uint32_t u[4]; short8 v; } t;
#pragma unroll
      for (int r = 0; r < 4; ++r) {
        float lo = w1[(k8 + 2 * r) * 256 + (kt * 16 + lcol) * 8 + h];
        float hi = w1[(k8 + 2 * r + 1) * 256 + (kt * 16 + lcol) * 8 + h];
        t.u[r] = cvt_pk_bf16(lo, hi);
      }
      bf[kt] = t.v;
    }
#pragma unroll
    for (int t = 0; t < 2; ++t) {
      int mt_ = w + t * 4;                 // tile 0..7 (rows mt_*16..+15)
      int frow = f0 + mt_ * 16 + lcol;
      if (frow > 511) frow = 511;          // row 127 junk, never read
      const float* ep = epos + (frow * NH + h) * 32 + k8;
      short8 af = pack8(*(const f32x4*)ep, *(const f32x4*)(ep + 4));
#pragma unroll
      for (int kt = 0; kt < 2; ++kt) {
        f32x4 d = __builtin_amdgcn_mfma_f32_16x16x32_bf16(af, bf[kt], zero, 0, 0, 0);
#pragma unroll
        for (int r = 0; r < 4; ++r)
          sAp[mt_ * 16 + kb * 4 + r][kt * 16 + lcol] = d[r];
      }
    }
  } else {                                 // Ai (waves 4,5) / Aj (waves 6,7)
    int isI = w < 6;
    int p0 = isI ? ((kb < 2 ? 32 : 48) + k8)    // W_i rows: 32..47 | 64..79
                 : ((kb < 2 ? 48 : 64) + k8);   // W_j rows: 48..63 | 80..95
    short8 bf[2];
#pragma unroll
    for (int kt = 0; kt < 2; ++kt) {
      union { uint32_t u[4]; short8 v; } t;
#pragma unroll
      for (int r = 0; r < 4; ++r) {
        float lo = w1[(p0 + 2 * r) * 256 + (kt * 16 + lcol) * 8 + h];
        float hi = w1[(p0 + 2 * r + 1) * 256 + (kt * 16 + lcol) * 8 + h];
        t.u[r] = cvt_pk_bf16(lo, hi);
      }
      bf[kt] = t.v;
    }
    const float* eB = isI ? ebi : ebj;
    const float* eC = isI ? eci : ecj;
    int base = isI ? m0 : n0;
    int w2_ = isI ? (w - 4) : (w - 6);
#pragma unroll
    for (int t = 0; t < 2; ++t) {
      int mt_ = w2_ * 2 + t;               // tile 0..3 (rows mt_*16..+15)
      int gm = b * SEQ + base + mt_ * 16 + lcol;
      int bi = bseq[gm], ci = cseq[gm];
      const float* src = (kb < 2) ? eB + (bi * NH + h) * 16 + k8
                                  : eC + (ci * NH + h) * 16 + (k8 - 16);
      short8 af = pack8(*(const f32x4*)src, *(const f32x4*)(src + 4));
#pragma unroll
      for (int kt = 0; kt < 2; ++kt) {
        f32x4 d = __builtin_amdgcn_mfma_f32_16x16x32_bf16(af, bf[kt], zero, 0, 0, 0);
#pragma unroll
        for (int r = 0; r < 4; ++r) {
          float* T = isI ? &sAi[mt_ * 16 + kb * 4 + r][kt * 16 + lcol]
                         : &sAj[mt_ * 16 + kb * 4 + r][kt * 16 + lcol];
          *T = d[r];
        }
      }
    }
  }
  __syncthreads();

  // ---------------- phase 2: main compute (ILP-batched) ----------------
  union { uint32_t u[4]; short8 v; } w2f;  // A = w2^T: row=lcol, k=k8..k8+7
#pragma unroll
  for (int r = 0; r < 4; ++r) {
    float lo = w2[(k8 + 2 * r) * 128 + lcol * 8 + h];
    float hi = w2[(k8 + 2 * r + 1) * 128 + lcol * 8 + h];
    w2f.u[r] = cvt_pk_bf16(lo, hi);
  }
  float w3v[4];
#pragma unroll
  for (int r = 0; r < 4; ++r) w3v[r] = w3[(kb * 4 + r) * 8 + h];

  // hoist Aj for all 4 ng (constant across both s-steps)
  f32x4 ajA[4], ajB[4];
#pragma unroll
  for (int ng = 0; ng < 4; ++ng) {
    int nl = ng * 16 + lcol;
    ajA[ng] = *(const f32x4*)&sAj[nl][k8];
    ajB[ng] = *(const f32x4*)&sAj[nl][k8 + 4];
  }

  const float* attn_b = attn + (b * NH + h) * SEQ * SEQ;
  float* out_b = out + (b * NH + h) * SEQ * SEQ;
  int bit4 = kb & 1, bit5 = kb & 2;

#pragma unroll
  for (int s = 0; s < 2; ++s) {
    int mb = w * 8 + s * 4;
    float av[4];
    int idxs[4];
#pragma unroll
    for (int ng = 0; ng < 4; ++ng) {
      idxs[ng] = (m0 + mb + kb) * SEQ + n0 + ng * 16 + lcol;
      av[ng] = attn_b[idxs[ng]];
    }
    // Ai rows for this s-step's 4 m's
    f32x4 aiA[4], aiB[4];
#pragma unroll
    for (int mi = 0; mi < 4; ++mi) {
      aiA[mi] = *(const f32x4*)&sAi[mb + mi][k8];
      aiB[mi] = *(const f32x4*)&sAi[mb + mi][k8 + 4];
    }
#pragma unroll
    for (int ng = 0; ng < 4; ++ng) {
      int nl = ng * 16 + lcol;
      // batch-load all Apos operands for the 4 chains
      f32x4 pA[4], pB[4];
#pragma unroll
      for (int mi = 0; mi < 4; ++mi) {
        int rl = mb + mi - nl + 63;
        pA[mi] = *(const f32x4*)&sAp[rl][k8];
        pB[mi] = *(const f32x4*)&sAp[rl][k8 + 4];
      }
      __builtin_amdgcn_sched_barrier(0);
      float part[4];
#pragma unroll
      for (int mi = 0; mi < 4; ++mi) {
        f32x4 s0 = pA[mi] + aiA[mi] + ajA[ng];
        f32x4 s1 = pB[mi] + aiB[mi] + ajB[ng];
        union { uint32_t u[4]; short8 v; } ef;
        ef.u[0] = cvt_pk_bf16(fmaxf(s0[0], 0.f), fmaxf(s0[1], 0.f));
        ef.u[1] = cvt_pk_bf16(fmaxf(s0[2], 0.f), fmaxf(s0[3], 0.f));
        ef.u[2] = cvt_pk_bf16(fmaxf(s1[0], 0.f), fmaxf(s1[1], 0.f));
        ef.u[3] = cvt_pk_bf16(fmaxf(s1[2], 0.f), fmaxf(s1[3], 0.f));
        f32x4 d = __builtin_amdgcn_mfma_f32_16x16x32_bf16(w2f.v, ef.v, zero, 0, 0, 0);
        part[mi] = fmaxf(d[0], 0.f) * w3v[0] + fmaxf(d[1], 0.f) * w3v[1] +
                   fmaxf(d[2], 0.f) * w3v[2] + fmaxf(d[3], 0.f) * w3v[3];
      }
      // 3-shuffle butterfly reduce (validated r6): lane(kb) <- total part[kb]
      float mineA = bit4 ? part[1] : part[0];
      float sendA = bit4 ? part[0] : part[1];
      float mineB = bit4 ? part[3] : part[2];
      float sendB = bit4 ? part[2] : part[3];
      mineA += __shfl_xor(sendA, 16, 64);
      mineB += __shfl_xor(sendB, 16, 64);
      float keep = bit5 ? mineB : mineA;
      float send = bit5 ? mineA : mineB;
      float res = keep + __shfl_xor(send, 32, 64);
      out_b[idxs[ng]] = av[ng] + res;
    }
  }
}

extern "C" void kernel_launch(void* const* d_in, const int* in_sizes, int n_in,
                              void* d_out, int out_size, void* d_ws, size_t ws_size,
                              hipStream_t stream) {
  const float* attn = (const float*)d_in[0];
  const int* bseq   = (const int*)d_in[1];
  const int* cseq   = (const int*)d_in[2];
  const float* epos = (const float*)d_in[3];
  const float* ebi  = (const float*)d_in[4];
  const float* ebj  = (const float*)d_in[5];
  const float* eci  = (const float*)d_in[6];
  const float* ecj  = (const float*)d_in[7];
  const float* w1   = (const float*)d_in[8];
  const float* w2   = (const float*)d_in[9];
  const float* w3   = (const float*)d_in[10];
  float* out = (float*)d_out;

  hipLaunchKernelGGL(dis_att_fused, dim3(512), dim3(512), 0, stream,
                     attn, bseq, cseq, epos, ebi, ebj, eci, ecj, w1, w2, w3, out);
}